// Round 5
// baseline (212.560 us; speedup 1.0000x reference)
//
#include <hip/hip_runtime.h>

#define LYS 12
#define LXS 120   // 10*LYS; strides ≡ 0 mod 4 words -> aligned ds_read_b128 line reads

typedef _Float16 h4 __attribute__((ext_vector_type(4)));

// 27 taps as named SSA values. f16 storage: 54 VGPRs total so the live set fits
// the allocator's immovable 84-reg target (R2-R4: f32 needed 108+ -> remat =
// 3.6GB/dispatch L2 weight stream = 80% of L2 ceiling = the measured wall).
#define R9A(M) M(0) M(1) M(2) M(3) M(4) M(5) M(6) M(7) M(8)
#define R9B(M) M(9) M(10) M(11) M(12) M(13) M(14) M(15) M(16) M(17)
#define R9C(M) M(18) M(19) M(20) M(21) M(22) M(23) M(24) M(25) M(26)

#define LOADW(T) float4 f##T = *(const float4*)(W + ((size_t)(T) << 18) + ofs);
#define CVTW(T)  h4 w##T = { (_Float16)f##T.x, (_Float16)f##T.y, \
                             (_Float16)f##T.z, (_Float16)f##T.w }; \
                 sw0 += (float)w##T.x; sw1 += (float)w##T.y; \
                 sw2 += (float)w##T.z; sw3 += (float)w##T.w;

// one (dx,dy) line: 6-float z-window (16B-aligned: all strides ≡ 0 mod 4 words),
// 12 fma_mix ops, 3 taps
#define LINE(SRC, dx, dy, WA, WB, WC) {                                       \
    const float* p = &SRC[(lx + (dx)) * LXS + (ly + (dy)) * LYS + 4 * h];     \
    const float4 va = *(const float4*)p;                                      \
    const float2 vb = *(const float2*)(p + 4);                                \
    d0 += (float)WA.x * va.x; d1 += (float)WA.y * va.y;                       \
    d2 += (float)WA.z * va.z; d3 += (float)WA.w * va.w;                       \
    d0 += (float)WB.x * va.y; d1 += (float)WB.y * va.z;                       \
    d2 += (float)WB.z * va.w; d3 += (float)WB.w * vb.x;                       \
    d0 += (float)WC.x * va.z; d1 += (float)WC.y * va.w;                       \
    d2 += (float)WC.z * vb.x; d3 += (float)WC.w * vb.y; }

#define RFL(x) __int_as_float(__builtin_amdgcn_readfirstlane(__float_as_int(x)))

// one inner iteration: read SRC, write DST (double-buffer -> single barrier)
#define ITER(SRC, DST, RED) {                                                 \
    float mean = (halo_s + Si) * inv_n;                                       \
    float istd = rsqrtf((halo_q + Qi) * inv_n - mean * mean + 1e-5f);         \
    float d0 = 0.f, d1 = 0.f, d2 = 0.f, d3 = 0.f;                             \
    LINE(SRC, 0, 0, w0,  w1,  w2)                                             \
    LINE(SRC, 0, 1, w3,  w4,  w5)                                             \
    LINE(SRC, 0, 2, w6,  w7,  w8)                                             \
    LINE(SRC, 1, 0, w9,  w10, w11)                                            \
    LINE(SRC, 1, 1, w12, w13, w14)                                            \
    LINE(SRC, 1, 2, w15, w16, w17)                                            \
    LINE(SRC, 2, 0, w18, w19, w20)                                            \
    LINE(SRC, 2, 1, w21, w22, w23)                                            \
    LINE(SRC, 2, 2, w24, w25, w26)                                            \
    float u0 = (d0 - mean * sw0) * istd + (float)bh.x;                        \
    float u1 = (d1 - mean * sw1) * istd + (float)bh.y;                        \
    float u2 = (d2 - mean * sw2) * istd + (float)bh.z;                        \
    float u3 = (d3 - mean * sw3) * istd + (float)bh.w;                        \
    c0 += (float)rh.x * (u0 / (1.f + __expf(-u0)));                           \
    c1 += (float)rh.y * (u1 / (1.f + __expf(-u1)));                           \
    c2 += (float)rh.z * (u2 / (1.f + __expf(-u2)));                           \
    c3 += (float)rh.w * (u3 / (1.f + __expf(-u3)));                           \
    DST[ip]     = c0;                                                         \
    DST[ip + 1] = c1;                                                         \
    DST[ip + 2] = c2;                                                         \
    DST[ip + 3] = c3;                                                         \
    float b0 = c0 + c1 + c2 + c3;                                             \
    float b1 = c0 * c0 + c1 * c1 + c2 * c2 + c3 * c3;                         \
    _Pragma("unroll")                                                         \
    for (int off = 32; off; off >>= 1) {                                      \
        b0 += __shfl_xor(b0, off);                                            \
        b1 += __shfl_xor(b1, off);                                            \
    }                                                                         \
    if (lane == 0) RED[wave] = make_float2(b0, b1);                           \
    __syncthreads();                                                          \
    Si = RFL(RED[0].x + RED[1].x);                                            \
    Qi = RFL(RED[0].y + RED[1].y); }

__global__ __launch_bounds__(128)
void gridnet_kernel(const float* __restrict__ W,
                    const float* __restrict__ Bias,
                    const float* __restrict__ Rs,
                    const float* __restrict__ X,
                    float* __restrict__ Y,
                    int n_batch)
{
    __shared__ __align__(16) float buf0[10 * LXS];
    __shared__ __align__(16) float buf1[10 * LXS];
    __shared__ float4 red4[2];
    __shared__ float2 redA[2], redB[2];

    const int tid  = threadIdx.x;
    const int h    = tid & 1;            // z-half: outputs z = 4h..4h+3
    const int ly   = (tid >> 1) & 7;
    const int lx   = tid >> 4;
    const int wave = tid >> 6;
    const int lane = tid & 63;

    const int bid   = blockIdx.x;
    const int r     = bid / n_batch;     // spatial block 0..511
    const int batch = bid - r * n_batch; // batch-fast: 16 weight-sharers adjacent
    const int gm0 = (r >> 6) << 3;
    const int gn0 = ((r >> 3) & 7) << 3;
    const int gk0 = (r & 7) << 3;

    const float* xb = X + ((size_t)batch << 18);

    // ---- stage 10x10x10 raw block (zero halo) into BOTH buffers; total sums ----
    float s_all = 0.f, q_all = 0.f;
    for (int i = tid; i < 1000; i += 128) {
        int ix = i / 100;
        int rem = i - ix * 100;
        int iy = rem / 10;
        int iz = rem - iy * 10;
        int m = gm0 + ix - 1, n = gn0 + iy - 1, k = gk0 + iz - 1;
        float v = 0.f;
        if ((unsigned)m < 64u && (unsigned)n < 64u && (unsigned)k < 64u)
            v = xb[(m << 12) + (n << 6) + k];
        int a = ix * LXS + iy * LYS + iz;
        buf0[a] = v;
        buf1[a] = v;   // halo (frozen) must exist in both buffers
        s_all += v;
        q_all += v * v;
    }

    // ---- per-thread params: 27 taps x 4 z, f16-packed, register-resident ----
    const int gm = gm0 + lx, gn = gn0 + ly, gk = gk0 + 4 * h;
    const size_t ofs = ((size_t)gm << 12) + (gn << 6) + gk;

    float sw0 = 0.f, sw1 = 0.f, sw2 = 0.f, sw3 = 0.f;
    R9A(LOADW) R9A(CVTW)     // 3 groups of 9 to cap transient f32 pressure
    R9B(LOADW) R9B(CVTW)
    R9C(LOADW) R9C(CVTW)
    float4 bf = *(const float4*)(Bias + ofs);
    float4 rf = *(const float4*)(Rs + ofs);
    h4 bh = { (_Float16)bf.x, (_Float16)bf.y, (_Float16)bf.z, (_Float16)bf.w };
    h4 rh = { (_Float16)rf.x, (_Float16)rf.y, (_Float16)rf.z, (_Float16)rf.w };

    __syncthreads();

    const int ip = (lx + 1) * LXS + (ly + 1) * LYS + (4 * h + 1);
    float c0 = buf0[ip], c1 = buf0[ip + 1], c2 = buf0[ip + 2], c3 = buf0[ip + 3];

    // ---- one-time reduction: total + interior sums -> frozen halo sums ----
    float a0 = s_all, a1 = q_all;
    float a2 = c0 + c1 + c2 + c3;
    float a3 = c0 * c0 + c1 * c1 + c2 * c2 + c3 * c3;
    #pragma unroll
    for (int off = 32; off; off >>= 1) {
        a0 += __shfl_xor(a0, off);
        a1 += __shfl_xor(a1, off);
        a2 += __shfl_xor(a2, off);
        a3 += __shfl_xor(a3, off);
    }
    if (lane == 0) red4[wave] = make_float4(a0, a1, a2, a3);
    __syncthreads();
    float4 t0 = red4[0], t1 = red4[1];
    const float halo_s = RFL((t0.x + t1.x) - (t0.z + t1.z));
    const float halo_q = RFL((t0.y + t1.y) - (t0.w + t1.w));
    float Si = RFL(t0.z + t1.z);
    float Qi = RFL(t0.w + t1.w);

    const float inv_n = 1.0f / 1000.0f;

    // 8 iterations = 4 ping-pong pairs; one barrier per iteration
    #pragma unroll 1
    for (int it = 0; it < 4; ++it) {
        ITER(buf0, buf1, redA)
        ITER(buf1, buf0, redB)
    }

    *(float4*)(Y + ((size_t)batch << 18) + ofs) = make_float4(c0, c1, c2, c3);
}

extern "C" void kernel_launch(void* const* d_in, const int* in_sizes, int n_in,
                              void* d_out, int out_size, void* d_ws, size_t ws_size,
                              hipStream_t stream) {
    const float* W = (const float*)d_in[0];   // (27,64,64,64)
    const float* B = (const float*)d_in[1];   // (64,64,64)
    const float* R = (const float*)d_in[2];   // (64,64,64)
    const float* X = (const float*)d_in[3];   // (16,64,64,64)
    float* Y = (float*)d_out;

    int n_batch = in_sizes[3] >> 18;          // 64^3 per sample
    dim3 grid(512 * n_batch), block(128);
    hipLaunchKernelGGL(gridnet_kernel, grid, block, 0, stream, W, B, R, X, Y, n_batch);
}

// Round 7
// 184.595 us; speedup vs baseline: 1.1515x; 1.1515x over previous
//
#include <hip/hip_runtime.h>

typedef _Float16 h2 __attribute__((ext_vector_type(2)));

#define COLH 10   // halves per z-column (z = 0..9); column stride = 5 dwords (odd -> bank spread)

// ---- DPP wave-64 sum (VALU pipe, not LDS pipe): result valid in lane 63 ----
template <int CTRL>
__device__ __forceinline__ float dpp_stage(float v) {
    int x = __builtin_amdgcn_update_dpp(0, __float_as_int(v), CTRL, 0xf, 0xf, true);
    return v + __int_as_float(x);
}
__device__ __forceinline__ float wave_sum(float v) {
    v = dpp_stage<0x111>(v);  // row_shr:1
    v = dpp_stage<0x112>(v);  // row_shr:2
    v = dpp_stage<0x114>(v);  // row_shr:4
    v = dpp_stage<0x118>(v);  // row_shr:8
    v = dpp_stage<0x142>(v);  // row_bcast:15
    v = dpp_stage<0x143>(v);  // row_bcast:31
    return v;                 // lane 63 holds the full sum
}

#define RFL(x) __int_as_float(__builtin_amdgcn_readfirstlane(__float_as_int(x)))

// ---- 27 taps as named half2 SSA values: 27 VGPRs total -> live set ~50 < the
// allocator's immovable 84-reg target (R2-R5: 54+ reg f32/f16x4 schemes got
// remat'd into a 3.6GB/dispatch L2 weight stream or spilled). ----
#define R9A(M) M(0) M(1) M(2) M(3) M(4) M(5) M(6) M(7) M(8)
#define R9B(M) M(9) M(10) M(11) M(12) M(13) M(14) M(15) M(16) M(17)
#define R9C(M) M(18) M(19) M(20) M(21) M(22) M(23) M(24) M(25) M(26)

#define LOADW(T) float2 f##T = *(const float2*)(W + ((size_t)(T) << 18) + ofs);
#define CVTW(T)  h2 w##T = { (_Float16)f##T.x, (_Float16)f##T.y }; \
                 sw0 += (float)w##T.x; sw1 += (float)w##T.y;

// one (dx,dy) line: f16 z-window [2h..2h+3] = two 4B-aligned half2 loads
// (ds_read2_b32); 6 v_fma_mix_f32 (both srcs f16), 3 taps, 2 outputs
#define LINE(SRC, dx, dy, WA, WB, WC) {                                       \
    const _Float16* p = &SRC[(((lx + (dx)) * 10) + (ly + (dy))) * COLH + 2 * h]; \
    const h2 v0 = *(const h2*)p;                                              \
    const h2 v1 = *(const h2*)(p + 2);                                        \
    d0 += (float)v0.x * (float)WA.x;                                          \
    d0 += (float)v0.y * (float)WB.x;                                          \
    d0 += (float)v1.x * (float)WC.x;                                          \
    d1 += (float)v0.y * (float)WA.y;                                          \
    d1 += (float)v1.x * (float)WB.y;                                          \
    d1 += (float)v1.y * (float)WC.y; }

// one inner iteration: read SRC, write DST (ping-pong -> single barrier)
#define ITER(SRC, DST, RED) {                                                 \
    float mean = (halo_s + Si) * inv_n;                                       \
    float istd = rsqrtf((halo_q + Qi) * inv_n - mean * mean + 1e-5f);         \
    float d0 = 0.f, d1 = 0.f;                                                 \
    LINE(SRC, 0, 0, w0,  w1,  w2)                                             \
    LINE(SRC, 0, 1, w3,  w4,  w5)                                             \
    LINE(SRC, 0, 2, w6,  w7,  w8)                                             \
    LINE(SRC, 1, 0, w9,  w10, w11)                                            \
    LINE(SRC, 1, 1, w12, w13, w14)                                            \
    LINE(SRC, 1, 2, w15, w16, w17)                                            \
    LINE(SRC, 2, 0, w18, w19, w20)                                            \
    LINE(SRC, 2, 1, w21, w22, w23)                                            \
    LINE(SRC, 2, 2, w24, w25, w26)                                            \
    float u0 = (d0 - mean * sw0) * istd + bias0;                              \
    float u1 = (d1 - mean * sw1) * istd + bias1;                              \
    c0 += rs0 * (u0 / (1.f + __expf(-u0)));                                   \
    c1 += rs1 * (u1 / (1.f + __expf(-u1)));                                   \
    DST[ipc]     = (_Float16)c0;                                              \
    DST[ipc + 1] = (_Float16)c1;                                              \
    float b0 = wave_sum(c0 + c1);                                             \
    float b1 = wave_sum(c0 * c0 + c1 * c1);                                   \
    if (lane == 63) RED[wave] = make_float2(b0, b1);                          \
    __syncthreads();                                                          \
    Si = RFL(RED[0].x + RED[1].x + RED[2].x + RED[3].x);                      \
    Qi = RFL(RED[0].y + RED[1].y + RED[2].y + RED[3].y); }

__global__ __launch_bounds__(256)
void gridnet_kernel(const float* __restrict__ W,
                    const float* __restrict__ Bias,
                    const float* __restrict__ Rs,
                    const float* __restrict__ X,
                    float* __restrict__ Y,
                    int n_batch)
{
    __shared__ __align__(16) _Float16 buf0[100 * COLH];   // 2 KB each
    __shared__ __align__(16) _Float16 buf1[100 * COLH];
    __shared__ float4 red4[4];
    __shared__ float2 redA[4], redB[4];

    const int tid  = threadIdx.x;
    const int h    = tid & 3;            // z-quarter: outputs z = 2h, 2h+1 (block-local)
    const int ly   = (tid >> 2) & 7;
    const int lx   = tid >> 5;
    const int wave = tid >> 6;
    const int lane = tid & 63;

    const int bid   = blockIdx.x;
    const int r     = bid / n_batch;     // spatial block 0..511
    const int batch = bid - r * n_batch; // batch-fast: 16 weight-sharers adjacent
    const int gm0 = (r >> 6) << 3;
    const int gn0 = ((r >> 3) & 7) << 3;
    const int gk0 = (r & 7) << 3;

    const float* xb = X + ((size_t)batch << 18);

    // ---- stage 10x10x10 block (zero halo) into BOTH f16 buffers; sums on the fly ----
    float s_all = 0.f, q_all = 0.f, s_int = 0.f, q_int = 0.f;
    for (int i = tid; i < 1000; i += 256) {
        int ix = i / 100;
        int rem = i - ix * 100;
        int iy = rem / 10;
        int iz = rem - iy * 10;
        int m = gm0 + ix - 1, n = gn0 + iy - 1, k = gk0 + iz - 1;
        float v = 0.f;
        if ((unsigned)m < 64u && (unsigned)n < 64u && (unsigned)k < 64u)
            v = xb[(m << 12) + (n << 6) + k];
        _Float16 hv = (_Float16)v;
        int a = (ix * 10 + iy) * COLH + iz;
        buf0[a] = hv;
        buf1[a] = hv;                     // frozen halo must exist in both buffers
        float vf = (float)hv;             // stats over the values the dot will see
        s_all += vf;
        q_all += vf * vf;
        bool interior = ((unsigned)(ix - 1) < 8u) & ((unsigned)(iy - 1) < 8u) &
                        ((unsigned)(iz - 1) < 8u);
        if (interior) { s_int += vf; q_int += vf * vf; }
    }

    // ---- per-thread params: 27 taps x 2 z as half2, register-resident ----
    const int gm = gm0 + lx, gn = gn0 + ly, gk = gk0 + 2 * h;
    const size_t ofs = ((size_t)gm << 12) + (gn << 6) + gk;

    float sw0 = 0.f, sw1 = 0.f;
    R9A(LOADW) R9A(CVTW)                  // 3 groups of 9 caps transient f32 pressure
    R9B(LOADW) R9B(CVTW)
    R9C(LOADW) R9C(CVTW)
    const float2 bf = *(const float2*)(Bias + ofs);
    const float2 rf = *(const float2*)(Rs + ofs);
    const float bias0 = bf.x, bias1 = bf.y;
    const float rs0 = rf.x, rs1 = rf.y;

    __syncthreads();

    const int ipc = ((lx + 1) * 10 + (ly + 1)) * COLH + (2 * h + 1);
    float c0 = (float)buf0[ipc];
    float c1 = (float)buf0[ipc + 1];

    // ---- one-time reduction: total + interior sums -> frozen halo sums ----
    float a0 = wave_sum(s_all);
    float a1 = wave_sum(q_all);
    float a2 = wave_sum(s_int);
    float a3 = wave_sum(q_int);
    if (lane == 63) red4[wave] = make_float4(a0, a1, a2, a3);
    __syncthreads();
    float S_all = 0.f, Q_all = 0.f, Si = 0.f, Qi = 0.f;
    #pragma unroll
    for (int wv = 0; wv < 4; ++wv) {
        float4 t4 = red4[wv];
        S_all += t4.x; Q_all += t4.y; Si += t4.z; Qi += t4.w;
    }
    const float halo_s = RFL(S_all - Si);
    const float halo_q = RFL(Q_all - Qi);
    Si = RFL(Si);
    Qi = RFL(Qi);

    const float inv_n = 1.0f / 1000.0f;

    // 8 iterations = 4 ping-pong pairs; one barrier per iteration
    #pragma unroll 1
    for (int it = 0; it < 4; ++it) {
        ITER(buf0, buf1, redA)
        ITER(buf1, buf0, redB)
    }

    *(float2*)(Y + ((size_t)batch << 18) + ofs) = make_float2(c0, c1);
}

extern "C" void kernel_launch(void* const* d_in, const int* in_sizes, int n_in,
                              void* d_out, int out_size, void* d_ws, size_t ws_size,
                              hipStream_t stream) {
    const float* W = (const float*)d_in[0];   // (27,64,64,64)
    const float* B = (const float*)d_in[1];   // (64,64,64)
    const float* R = (const float*)d_in[2];   // (64,64,64)
    const float* X = (const float*)d_in[3];   // (16,64,64,64)
    float* Y = (float*)d_out;

    int n_batch = in_sizes[3] >> 18;          // 64^3 per sample
    dim3 grid(512 * n_batch), block(256);
    hipLaunchKernelGGL(gridnet_kernel, grid, block, 0, stream, W, B, R, X, Y, n_batch);
}

// Round 8
// 167.263 us; speedup vs baseline: 1.2708x; 1.1036x over previous
//
#include <hip/hip_runtime.h>

typedef _Float16 h2 __attribute__((ext_vector_type(2)));

#define COLH 10   // halves per z-column; column stride = 5 dwords (odd -> bank spread)

// ---- DPP wave-64 sum (VALU pipe, not LDS pipe): result valid in lane 63 ----
template <int CTRL>
__device__ __forceinline__ float dpp_stage(float v) {
    int x = __builtin_amdgcn_update_dpp(0, __float_as_int(v), CTRL, 0xf, 0xf, true);
    return v + __int_as_float(x);
}
__device__ __forceinline__ float wave_sum(float v) {
    v = dpp_stage<0x111>(v);  // row_shr:1
    v = dpp_stage<0x112>(v);  // row_shr:2
    v = dpp_stage<0x114>(v);  // row_shr:4
    v = dpp_stage<0x118>(v);  // row_shr:8
    v = dpp_stage<0x142>(v);  // row_bcast:15
    v = dpp_stage<0x143>(v);  // row_bcast:31
    return v;                 // lane 63 holds the full sum
}

#define RFL(x) __int_as_float(__builtin_amdgcn_readfirstlane(__float_as_int(x)))

// 9 (dx,dy) lines; line L has taps (3L, 3L+1, 3L+2) = (A,B,C).
// Packed for v_dot2_f32_f16:
//   out0 (z=2h+1 padded): A.x*v[2h] + B.x*v[2h+1] + C.x*v[2h+2] = dot2(v0,pA) + v1.x*qq.x
//   out1 (z=2h+2 padded): A.y*v[2h+1] + B.y*v[2h+2] + C.y*v[2h+3] = dot2(v1,pB) + v0.y*qq.y
#define R9L(M) M(0) M(1) M(2) M(3) M(4) M(5) M(6) M(7) M(8)

#define LOADL(L) \
    float2 fa##L = *(const float2*)(W + ((size_t)(3*(L)    ) << 18) + ofs); \
    float2 fb##L = *(const float2*)(W + ((size_t)(3*(L) + 1) << 18) + ofs); \
    float2 fc##L = *(const float2*)(W + ((size_t)(3*(L) + 2) << 18) + ofs); \
    h2 pA##L = { (_Float16)fa##L.x, (_Float16)fb##L.x };                    \
    h2 pB##L = { (_Float16)fb##L.y, (_Float16)fc##L.y };                    \
    h2 qq##L = { (_Float16)fc##L.x, (_Float16)fa##L.y };                    \
    sw0 += (float)pA##L.x + (float)pA##L.y + (float)qq##L.x;                \
    sw1 += (float)qq##L.y + (float)pB##L.x + (float)pB##L.y;

// one line: ONE ds_read2_b32 (imm offsets off loop-invariant base) + 2 fdot2 + 2 fma_mix
#define LINE(BP, L) {                                                       \
    const h2 v0 = (BP)[(((L) / 3) * 10 + (L) % 3) * 5];                     \
    const h2 v1 = (BP)[(((L) / 3) * 10 + (L) % 3) * 5 + 1];                 \
    d0 = __builtin_amdgcn_fdot2(v0, pA##L, d0, false);                      \
    d1 = __builtin_amdgcn_fdot2(v1, pB##L, d1, false);                      \
    d0 += (float)v1.x * (float)qq##L.x;                                     \
    d1 += (float)v0.y * (float)qq##L.y; }

// one inner iteration: read SRC, write DST (ping-pong -> single barrier)
#define ITER(SRC, DST, RED) {                                               \
    const h2* bp = (const h2*)&SRC[base_h];                                 \
    float mean = (halo_s + Si) * inv_n;                                     \
    float istd = rsqrtf((halo_q + Qi) * inv_n - mean * mean + 1e-5f);       \
    float d0 = 0.f, d1 = 0.f;                                               \
    R9L(LINEM)                                                              \
    float u0 = (d0 - mean * sw0) * istd + bias0;                            \
    float u1 = (d1 - mean * sw1) * istd + bias1;                            \
    c0 += rs0 * (u0 * __builtin_amdgcn_rcpf(1.f + __expf(-u0)));            \
    c1 += rs1 * (u1 * __builtin_amdgcn_rcpf(1.f + __expf(-u1)));            \
    DST[ipc]     = (_Float16)c0;                                            \
    DST[ipc + 1] = (_Float16)c1;                                            \
    float b0 = wave_sum(c0 + c1);                                           \
    float b1 = wave_sum(c0 * c0 + c1 * c1);                                 \
    if (lane == 63) RED[wave] = make_float2(b0, b1);                        \
    __syncthreads();                                                        \
    Si = RFL(RED[0].x + RED[1].x + RED[2].x + RED[3].x);                    \
    Qi = RFL(RED[0].y + RED[1].y + RED[2].y + RED[3].y); }

#define LINEM(L) LINE(bp, L)

__global__ __launch_bounds__(256)
void gridnet_kernel(const float* __restrict__ W,
                    const float* __restrict__ Bias,
                    const float* __restrict__ Rs,
                    const float* __restrict__ X,
                    float* __restrict__ Y,
                    int n_batch)
{
    __shared__ __align__(16) _Float16 buf0[100 * COLH];   // 2 KB each
    __shared__ __align__(16) _Float16 buf1[100 * COLH];
    __shared__ float4 red4[4];
    __shared__ float2 redA[4], redB[4];

    const int tid  = threadIdx.x;
    const int h    = tid & 3;            // z-quarter: outputs z = 2h, 2h+1 (block-local)
    const int ly   = (tid >> 2) & 7;
    const int lx   = tid >> 5;
    const int wave = tid >> 6;
    const int lane = tid & 63;

    const int bid   = blockIdx.x;
    const int r     = bid / n_batch;     // spatial block 0..511
    const int batch = bid - r * n_batch; // batch-fast: 16 weight-sharers adjacent
    const int gm0 = (r >> 6) << 3;
    const int gn0 = ((r >> 3) & 7) << 3;
    const int gk0 = (r & 7) << 3;

    const float* xb = X + ((size_t)batch << 18);

    // ---- stage 10x10x10 block (zero halo) into BOTH f16 buffers; sums on the fly ----
    float s_all = 0.f, q_all = 0.f, s_int = 0.f, q_int = 0.f;
    for (int i = tid; i < 1000; i += 256) {
        int ix = i / 100;
        int rem = i - ix * 100;
        int iy = rem / 10;
        int iz = rem - iy * 10;
        int m = gm0 + ix - 1, n = gn0 + iy - 1, k = gk0 + iz - 1;
        float v = 0.f;
        if ((unsigned)m < 64u && (unsigned)n < 64u && (unsigned)k < 64u)
            v = xb[(m << 12) + (n << 6) + k];
        _Float16 hv = (_Float16)v;
        int a = (ix * 10 + iy) * COLH + iz;
        buf0[a] = hv;
        buf1[a] = hv;                     // frozen halo must exist in both buffers
        float vf = (float)hv;             // stats over the values the dot will see
        s_all += vf;
        q_all += vf * vf;
        bool interior = ((unsigned)(ix - 1) < 8u) & ((unsigned)(iy - 1) < 8u) &
                        ((unsigned)(iz - 1) < 8u);
        if (interior) { s_int += vf; q_int += vf * vf; }
    }

    // ---- per-thread params: 9 lines x 3 packed half2, register-resident (27 VGPRs) ----
    const int gm = gm0 + lx, gn = gn0 + ly, gk = gk0 + 2 * h;
    const size_t ofs = ((size_t)gm << 12) + (gn << 6) + gk;

    float sw0 = 0.f, sw1 = 0.f;
    R9L(LOADL)
    const float2 bf = *(const float2*)(Bias + ofs);
    const float2 rf = *(const float2*)(Rs + ofs);
    const float bias0 = bf.x, bias1 = bf.y;
    const float rs0 = rf.x, rs1 = rf.y;

    __syncthreads();

    // loop-invariant LDS geometry: window base (even half -> h2-aligned), write slot
    const int base_h = (lx * 10 + ly) * COLH + 2 * h;
    const int ipc    = ((lx + 1) * 10 + (ly + 1)) * COLH + (2 * h + 1);
    float c0 = (float)buf0[ipc];
    float c1 = (float)buf0[ipc + 1];

    // ---- one-time reduction: total + interior sums -> frozen halo sums ----
    float a0 = wave_sum(s_all);
    float a1 = wave_sum(q_all);
    float a2 = wave_sum(s_int);
    float a3 = wave_sum(q_int);
    if (lane == 63) red4[wave] = make_float4(a0, a1, a2, a3);
    __syncthreads();
    float S_all = 0.f, Q_all = 0.f, Si = 0.f, Qi = 0.f;
    #pragma unroll
    for (int wv = 0; wv < 4; ++wv) {
        float4 t4 = red4[wv];
        S_all += t4.x; Q_all += t4.y; Si += t4.z; Qi += t4.w;
    }
    const float halo_s = RFL(S_all - Si);
    const float halo_q = RFL(Q_all - Qi);
    Si = RFL(Si);
    Qi = RFL(Qi);

    const float inv_n = 1.0f / 1000.0f;

    // 8 iterations = 4 ping-pong pairs; one barrier per iteration
    #pragma unroll 1
    for (int it = 0; it < 4; ++it) {
        ITER(buf0, buf1, redA)
        ITER(buf1, buf0, redB)
    }

    *(float2*)(Y + ((size_t)batch << 18) + ofs) = make_float2(c0, c1);
}

extern "C" void kernel_launch(void* const* d_in, const int* in_sizes, int n_in,
                              void* d_out, int out_size, void* d_ws, size_t ws_size,
                              hipStream_t stream) {
    const float* W = (const float*)d_in[0];   // (27,64,64,64)
    const float* B = (const float*)d_in[1];   // (64,64,64)
    const float* R = (const float*)d_in[2];   // (64,64,64)
    const float* X = (const float*)d_in[3];   // (16,64,64,64)
    float* Y = (float*)d_out;

    int n_batch = in_sizes[3] >> 18;          // 64^3 per sample
    dim3 grid(512 * n_batch), block(256);
    hipLaunchKernelGGL(gridnet_kernel, grid, block, 0, stream, W, B, R, X, Y, n_batch);
}

// Round 9
// 166.445 us; speedup vs baseline: 1.2771x; 1.0049x over previous
//
#include <hip/hip_runtime.h>

typedef _Float16 h2 __attribute__((ext_vector_type(2)));

#define COLH 10   // halves per z-column; column stride = 5 dwords (odd -> bank spread)

// ---- DPP wave-64 sum (VALU pipe, not LDS pipe): result valid in lane 63 ----
template <int CTRL>
__device__ __forceinline__ float dpp_stage(float v) {
    int x = __builtin_amdgcn_update_dpp(0, __float_as_int(v), CTRL, 0xf, 0xf, true);
    return v + __int_as_float(x);
}
__device__ __forceinline__ float wave_sum(float v) {
    v = dpp_stage<0x111>(v);  // row_shr:1
    v = dpp_stage<0x112>(v);  // row_shr:2
    v = dpp_stage<0x114>(v);  // row_shr:4
    v = dpp_stage<0x118>(v);  // row_shr:8
    v = dpp_stage<0x142>(v);  // row_bcast:15
    v = dpp_stage<0x143>(v);  // row_bcast:31
    return v;                 // lane 63 holds the full sum
}

#define RFL(x) __int_as_float(__builtin_amdgcn_readfirstlane(__float_as_int(x)))

__device__ __forceinline__ h2 mid2(h2 lo, h2 hi) {
    // (lo.y, hi.x) as one whole-register op: v_alignbit_b32
    int r = __builtin_amdgcn_alignbit(__builtin_bit_cast(int, hi),
                                      __builtin_bit_cast(int, lo), 16);
    return __builtin_bit_cast(h2, r);
}

// ---- 27 taps as named half2 (out0,out1) SSA values: 27 VGPRs, register-resident ----
#define R27(M) M(0) M(1) M(2) M(3) M(4) M(5) M(6) M(7) M(8) M(9) M(10) M(11) \
    M(12) M(13) M(14) M(15) M(16) M(17) M(18) M(19) M(20) M(21) M(22) M(23)  \
    M(24) M(25) M(26)
#define R9L(M) M(0) M(1) M(2) M(3) M(4) M(5) M(6) M(7) M(8)

#define LOADW(T) float2 f##T = *(const float2*)(W + ((size_t)(T) << 18) + ofs); \
                 h2 w##T = { (_Float16)f##T.x, (_Float16)f##T.y };              \
                 sw0 += (float)w##T.x; sw1 += (float)w##T.y;

// one line L: 1 ds_read2_b32 + 1 alignbit + 3 v_pk_fma_f16 (NO scalar half extracts)
//   dd.x += v[2h+k]*wA.. taps (3L,3L+1,3L+2); dd = (d_out0, d_out1)
#define LINE(L, WA, WB, WC) {                                                 \
    const h2 v0 = bp[(((L) / 3) * 10 + (L) % 3) * 5];                         \
    const h2 v1 = bp[(((L) / 3) * 10 + (L) % 3) * 5 + 1];                     \
    const h2 vm = mid2(v0, v1);                                               \
    dd = __builtin_elementwise_fma(v0, WA, dd);                               \
    dd = __builtin_elementwise_fma(vm, WB, dd);                               \
    dd = __builtin_elementwise_fma(v1, WC, dd);  }

// one inner iteration: read SRC, write DST (ping-pong -> single barrier)
#define ITER(SRC, DST, RED) {                                                 \
    const h2* bp = (const h2*)&SRC[base_h];                                   \
    float mean = (halo_s + Si) * inv_n;                                       \
    float istd = rsqrtf((halo_q + Qi) * inv_n - mean * mean + 1e-5f);         \
    h2 dd = { (_Float16)0.f, (_Float16)0.f };                                 \
    LINE(0, w0,  w1,  w2)                                                     \
    LINE(1, w3,  w4,  w5)                                                     \
    LINE(2, w6,  w7,  w8)                                                     \
    LINE(3, w9,  w10, w11)                                                    \
    LINE(4, w12, w13, w14)                                                    \
    LINE(5, w15, w16, w17)                                                    \
    LINE(6, w18, w19, w20)                                                    \
    LINE(7, w21, w22, w23)                                                    \
    LINE(8, w24, w25, w26)                                                    \
    float u0 = ((float)dd.x - mean * sw0) * istd + bias0;                     \
    float u1 = ((float)dd.y - mean * sw1) * istd + bias1;                     \
    c0 += rs0 * (u0 * __builtin_amdgcn_rcpf(1.f + __expf(-u0)));              \
    c1 += rs1 * (u1 * __builtin_amdgcn_rcpf(1.f + __expf(-u1)));              \
    DST[ipc]     = (_Float16)c0;                                              \
    DST[ipc + 1] = (_Float16)c1;                                              \
    float b0 = wave_sum(c0 + c1);                                             \
    float b1 = wave_sum(c0 * c0 + c1 * c1);                                   \
    if (lane == 63) RED[wave] = make_float2(b0, b1);                          \
    __syncthreads();                                                          \
    Si = RFL(RED[0].x + RED[1].x + RED[2].x + RED[3].x);                      \
    Qi = RFL(RED[0].y + RED[1].y + RED[2].y + RED[3].y); }

__global__ __launch_bounds__(256)
void gridnet_kernel(const float* __restrict__ W,
                    const float* __restrict__ Bias,
                    const float* __restrict__ Rs,
                    const float* __restrict__ X,
                    float* __restrict__ Y,
                    int n_batch)
{
    __shared__ __align__(16) _Float16 buf0[100 * COLH];   // 2 KB each
    __shared__ __align__(16) _Float16 buf1[100 * COLH];
    __shared__ float4 red4[4];
    __shared__ float2 redA[4], redB[4];

    const int tid  = threadIdx.x;
    const int h    = tid & 3;            // z-quarter: outputs z = 2h, 2h+1 (block-local)
    const int ly   = (tid >> 2) & 7;
    const int lx   = tid >> 5;
    const int wave = tid >> 6;
    const int lane = tid & 63;

    const int bid   = blockIdx.x;
    const int r     = bid / n_batch;     // spatial block 0..511
    const int batch = bid - r * n_batch; // batch-fast: 16 weight-sharers adjacent
    const int gm0 = (r >> 6) << 3;
    const int gn0 = ((r >> 3) & 7) << 3;
    const int gk0 = (r & 7) << 3;

    const float* xb = X + ((size_t)batch << 18);

    // ---- stage 10x10x10 block (zero halo) into BOTH f16 buffers; sums on the fly ----
    float s_all = 0.f, q_all = 0.f, s_int = 0.f, q_int = 0.f;
    for (int i = tid; i < 1000; i += 256) {
        int ix = i / 100;
        int rem = i - ix * 100;
        int iy = rem / 10;
        int iz = rem - iy * 10;
        int m = gm0 + ix - 1, n = gn0 + iy - 1, k = gk0 + iz - 1;
        float v = 0.f;
        if ((unsigned)m < 64u && (unsigned)n < 64u && (unsigned)k < 64u)
            v = xb[(m << 12) + (n << 6) + k];
        _Float16 hv = (_Float16)v;
        int a = (ix * 10 + iy) * COLH + iz;
        buf0[a] = hv;
        buf1[a] = hv;                     // frozen halo must exist in both buffers
        float vf = (float)hv;             // stats over the values the dot will see
        s_all += vf;
        q_all += vf * vf;
        bool interior = ((unsigned)(ix - 1) < 8u) & ((unsigned)(iy - 1) < 8u) &
                        ((unsigned)(iz - 1) < 8u);
        if (interior) { s_int += vf; q_int += vf * vf; }
    }

    // ---- per-thread params: 27 taps x 2 z as half2, register-resident ----
    const int gm = gm0 + lx, gn = gn0 + ly, gk = gk0 + 2 * h;
    const size_t ofs = ((size_t)gm << 12) + (gn << 6) + gk;

    float sw0 = 0.f, sw1 = 0.f;
    R27(LOADW)
    const float2 bf = *(const float2*)(Bias + ofs);
    const float2 rf = *(const float2*)(Rs + ofs);
    const float bias0 = bf.x, bias1 = bf.y;
    const float rs0 = rf.x, rs1 = rf.y;

    __syncthreads();

    // loop-invariant LDS geometry: window base (even half -> h2-aligned), write slot
    const int base_h = (lx * 10 + ly) * COLH + 2 * h;
    const int ipc    = ((lx + 1) * 10 + (ly + 1)) * COLH + (2 * h + 1);
    float c0 = (float)buf0[ipc];
    float c1 = (float)buf0[ipc + 1];

    // ---- one-time reduction: total + interior sums -> frozen halo sums ----
    float a0 = wave_sum(s_all);
    float a1 = wave_sum(q_all);
    float a2 = wave_sum(s_int);
    float a3 = wave_sum(q_int);
    if (lane == 63) red4[wave] = make_float4(a0, a1, a2, a3);
    __syncthreads();
    float S_all = 0.f, Q_all = 0.f, Si = 0.f, Qi = 0.f;
    #pragma unroll
    for (int wv = 0; wv < 4; ++wv) {
        float4 t4 = red4[wv];
        S_all += t4.x; Q_all += t4.y; Si += t4.z; Qi += t4.w;
    }
    const float halo_s = RFL(S_all - Si);
    const float halo_q = RFL(Q_all - Qi);
    Si = RFL(Si);
    Qi = RFL(Qi);

    const float inv_n = 1.0f / 1000.0f;

    // 8 iterations = 4 ping-pong pairs; one barrier per iteration
    #pragma unroll 1
    for (int it = 0; it < 4; ++it) {
        ITER(buf0, buf1, redA)
        ITER(buf1, buf0, redB)
    }

    *(float2*)(Y + ((size_t)batch << 18) + ofs) = make_float2(c0, c1);
}

extern "C" void kernel_launch(void* const* d_in, const int* in_sizes, int n_in,
                              void* d_out, int out_size, void* d_ws, size_t ws_size,
                              hipStream_t stream) {
    const float* W = (const float*)d_in[0];   // (27,64,64,64)
    const float* B = (const float*)d_in[1];   // (64,64,64)
    const float* R = (const float*)d_in[2];   // (64,64,64)
    const float* X = (const float*)d_in[3];   // (16,64,64,64)
    float* Y = (float*)d_out;

    int n_batch = in_sizes[3] >> 18;          // 64^3 per sample
    dim3 grid(512 * n_batch), block(256);
    hipLaunchKernelGGL(gridnet_kernel, grid, block, 0, stream, W, B, R, X, Y, n_batch);
}